// Round 1
// baseline (1104.681 us; speedup 1.0000x reference)
//
#include <hip/hip_runtime.h>
#include <hip/hip_bf16.h>

// B=2, S=4096, D=768, H=12, HD=64
#define Sq 4096
#define Dm 768
#define Hh 12

typedef short short8 __attribute__((ext_vector_type(8)));
typedef float f32x4 __attribute__((ext_vector_type(4)));

__device__ inline unsigned short f2bf(float f) {
    unsigned int u = __builtin_bit_cast(unsigned int, f);
    u += 0x7fffu + ((u >> 16) & 1u);   // RNE
    return (unsigned short)(u >> 16);
}

__device__ inline short8 pack8(float4 a, float4 b) {
    short8 r;
    r[0] = (short)f2bf(a.x); r[1] = (short)f2bf(a.y);
    r[2] = (short)f2bf(a.z); r[3] = (short)f2bf(a.w);
    r[4] = (short)f2bf(b.x); r[5] = (short)f2bf(b.y);
    r[6] = (short)f2bf(b.z); r[7] = (short)f2bf(b.w);
    return r;
}

// out[m][n] = (sum_k X[m][k]*W[n][k] + bias[n]) * scale, written bf16 to
// dst in [B,H,S,HD] layout (head-split). M=8192, N=K=768.
__global__ __launch_bounds__(256) void proj_gemm(
    const float* __restrict__ X, const float* __restrict__ W,
    const float* __restrict__ bias, unsigned short* __restrict__ dst,
    float scale)
{
    const int lane = threadIdx.x & 63;
    const int wv   = threadIdx.x >> 6;
    const int l16  = lane & 15, quad = lane >> 4;
    const int m0 = blockIdx.x * 64 + wv * 16;
    const int n0 = blockIdx.y * 64;
    const int mrow = m0 + l16;

    f32x4 acc[4] = {};
    const float* xr = X + (size_t)mrow * Dm + quad * 8;
    for (int kk = 0; kk < Dm; kk += 32) {
        float4 a0 = *(const float4*)(xr + kk);
        float4 a1 = *(const float4*)(xr + kk + 4);
        short8 af = pack8(a0, a1);
#pragma unroll
        for (int nt = 0; nt < 4; ++nt) {
            const float* wr = W + (size_t)(n0 + nt * 16 + l16) * Dm + kk + quad * 8;
            float4 b0 = *(const float4*)(wr);
            float4 b1 = *(const float4*)(wr + 4);
            short8 bf = pack8(b0, b1);
            acc[nt] = __builtin_amdgcn_mfma_f32_16x16x32_bf16(af, bf, acc[nt], 0, 0, 0);
        }
    }
#pragma unroll
    for (int nt = 0; nt < 4; ++nt) {
        int col = n0 + nt * 16 + l16;
        float bv = bias[col];
        int h = col >> 6, hd = col & 63;
#pragma unroll
        for (int r = 0; r < 4; ++r) {
            int row = m0 + quad * 4 + r;          // 0..8191
            int b = row >> 12, s = row & 4095;
            float v = (acc[nt][r] + bv) * scale;
            dst[(((size_t)(b * Hh + h) * Sq + s) << 6) + hd] = f2bf(v);
        }
    }
}

// out[m][n] = sum_k Xb[m][k]*W[n][k] + bias[n], fp32 out, row-major.
__global__ __launch_bounds__(256) void out_gemm(
    const unsigned short* __restrict__ Xb, const float* __restrict__ W,
    const float* __restrict__ bias, float* __restrict__ out)
{
    const int lane = threadIdx.x & 63;
    const int wv   = threadIdx.x >> 6;
    const int l16  = lane & 15, quad = lane >> 4;
    const int m0 = blockIdx.x * 64 + wv * 16;
    const int n0 = blockIdx.y * 64;
    const int mrow = m0 + l16;

    f32x4 acc[4] = {};
    const unsigned short* xr = Xb + (size_t)mrow * Dm + quad * 8;
    for (int kk = 0; kk < Dm; kk += 32) {
        short8 af = *(const short8*)(xr + kk);
#pragma unroll
        for (int nt = 0; nt < 4; ++nt) {
            const float* wr = W + (size_t)(n0 + nt * 16 + l16) * Dm + kk + quad * 8;
            float4 b0 = *(const float4*)(wr);
            float4 b1 = *(const float4*)(wr + 4);
            short8 bf = pack8(b0, b1);
            acc[nt] = __builtin_amdgcn_mfma_f32_16x16x32_bf16(af, bf, acc[nt], 0, 0, 0);
        }
    }
#pragma unroll
    for (int nt = 0; nt < 4; ++nt) {
        int col = n0 + nt * 16 + l16;
        float bv = bias[col];
#pragma unroll
        for (int r = 0; r < 4; ++r) {
            int row = m0 + quad * 4 + r;
            out[(size_t)row * Dm + col] = acc[nt][r] + bv;
        }
    }
}

// Flash attention, causal. Q pre-scaled by 1/8. Q/K/V in [B*H, S, 64] bf16.
// One block = (b*h, 64-row q tile); 4 waves, 16 q-rows per wave.
__global__ __launch_bounds__(256) void attn(
    const unsigned short* __restrict__ Q, const unsigned short* __restrict__ K,
    const unsigned short* __restrict__ V, unsigned short* __restrict__ O)
{
    const int bh = blockIdx.x;            // 0..23
    const int qt = blockIdx.y;            // 0..63
    const int lane = threadIdx.x & 63;
    const int wv   = threadIdx.x >> 6;
    const int l16  = lane & 15, quad = lane >> 4;
    const int b = bh / Hh, h = bh % Hh;
    const size_t base = (size_t)bh * Sq * 64;
    const int q0 = qt * 64 + wv * 16;

    __shared__ unsigned short p_lds[4][16][72];  // stride 72: 16B-aligned rows, 2-way banks

    short8 qf[2];
    {
        const unsigned short* qp = Q + base + (size_t)(q0 + l16) * 64 + quad * 8;
        qf[0] = *(const short8*)(qp);
        qf[1] = *(const short8*)(qp + 32);
    }

    f32x4 oacc[4] = {};
    float m_i[4], l_i[4];
#pragma unroll
    for (int r = 0; r < 4; ++r) { m_i[r] = -__builtin_inff(); l_i[r] = 0.f; }

    for (int kt = 0; kt <= qt; ++kt) {
        const int kv0 = kt * 64;
        f32x4 s[4];
#pragma unroll
        for (int nt = 0; nt < 4; ++nt) {
            const unsigned short* kp = K + base + (size_t)(kv0 + nt * 16 + l16) * 64 + quad * 8;
            short8 k0 = *(const short8*)(kp);
            short8 k1 = *(const short8*)(kp + 32);
            f32x4 z = {};
            z     = __builtin_amdgcn_mfma_f32_16x16x32_bf16(qf[0], k0, z, 0, 0, 0);
            s[nt] = __builtin_amdgcn_mfma_f32_16x16x32_bf16(qf[1], k1, z, 0, 0, 0);
        }
        if (kt == qt) {   // only the diagonal tile needs masking
#pragma unroll
            for (int nt = 0; nt < 4; ++nt)
#pragma unroll
                for (int r = 0; r < 4; ++r) {
                    int col = kv0 + nt * 16 + l16;
                    int row = q0 + quad * 4 + r;
                    if (col > row) s[nt][r] = -__builtin_inff();
                }
        }
        float alpha[4];
#pragma unroll
        for (int r = 0; r < 4; ++r) {
            float mx = fmaxf(fmaxf(s[0][r], s[1][r]), fmaxf(s[2][r], s[3][r]));
#pragma unroll
            for (int off = 1; off < 16; off <<= 1)
                mx = fmaxf(mx, __shfl_xor(mx, off, 64));
            float mnew = fmaxf(m_i[r], mx);
            float a = __expf(m_i[r] - mnew);
            float ps = 0.f;
#pragma unroll
            for (int nt = 0; nt < 4; ++nt) {
                float p = __expf(s[nt][r] - mnew);
                s[nt][r] = p;
                ps += p;
            }
#pragma unroll
            for (int off = 1; off < 16; off <<= 1)
                ps += __shfl_xor(ps, off, 64);
            l_i[r] = l_i[r] * a + ps;
            m_i[r] = mnew;
            alpha[r] = a;
        }
#pragma unroll
        for (int ot = 0; ot < 4; ++ot)
#pragma unroll
            for (int r = 0; r < 4; ++r) oacc[ot][r] *= alpha[r];

        // P: C-layout regs -> LDS -> A-layout frags
#pragma unroll
        for (int nt = 0; nt < 4; ++nt)
#pragma unroll
            for (int r = 0; r < 4; ++r)
                p_lds[wv][quad * 4 + r][nt * 16 + l16] = f2bf(s[nt][r]);
        __syncthreads();
        short8 pf0 = *(const short8*)&p_lds[wv][l16][quad * 8];
        short8 pf1 = *(const short8*)&p_lds[wv][l16][32 + quad * 8];

#pragma unroll
        for (int ot = 0; ot < 4; ++ot) {
            short8 v0, v1;
#pragma unroll
            for (int j = 0; j < 8; ++j) {
                v0[j] = (short)V[base + (size_t)(kv0 + quad * 8 + j) * 64 + ot * 16 + l16];
                v1[j] = (short)V[base + (size_t)(kv0 + 32 + quad * 8 + j) * 64 + ot * 16 + l16];
            }
            oacc[ot] = __builtin_amdgcn_mfma_f32_16x16x32_bf16(pf0, v0, oacc[ot], 0, 0, 0);
            oacc[ot] = __builtin_amdgcn_mfma_f32_16x16x32_bf16(pf1, v1, oacc[ot], 0, 0, 0);
        }
        __syncthreads();
    }

#pragma unroll
    for (int r = 0; r < 4; ++r) {
        float inv = 1.f / l_i[r];
        int srow = q0 + quad * 4 + r;
#pragma unroll
        for (int ot = 0; ot < 4; ++ot) {
            int hd = ot * 16 + l16;
            O[((size_t)(b * Sq + srow)) * Dm + h * 64 + hd] = f2bf(oacc[ot][r] * inv);
        }
    }
}

extern "C" void kernel_launch(void* const* d_in, const int* in_sizes, int n_in,
                              void* d_out, int out_size, void* d_ws, size_t ws_size,
                              hipStream_t stream) {
    const float* q  = (const float*)d_in[0];
    const float* k  = (const float*)d_in[1];
    const float* v  = (const float*)d_in[2];
    // d_in[3]: causal mask — implemented analytically
    const float* Wq = (const float*)d_in[4];  const float* bq = (const float*)d_in[5];
    const float* Wk = (const float*)d_in[6];  const float* bk = (const float*)d_in[7];
    const float* Wv = (const float*)d_in[8];  const float* bv = (const float*)d_in[9];
    const float* Wo = (const float*)d_in[10]; const float* bo = (const float*)d_in[11];
    float* out = (float*)d_out;

    const size_t NTOK = (size_t)2 * Sq * Dm;  // 6291456 elements
    unsigned short* qb = (unsigned short*)d_ws;
    unsigned short* kb = qb + NTOK;
    unsigned short* vb = kb + NTOK;
    unsigned short* ob = vb + NTOK;

    dim3 bb(256);
    dim3 gg(8192 / 64, Dm / 64);   // (128, 12)
    proj_gemm<<<gg, bb, 0, stream>>>(q, Wq, bq, qb, 0.125f);  // fold 1/sqrt(64) into Q
    proj_gemm<<<gg, bb, 0, stream>>>(k, Wk, bk, kb, 1.0f);
    proj_gemm<<<gg, bb, 0, stream>>>(v, Wv, bv, vb, 1.0f);
    attn<<<dim3(2 * Hh, Sq / 64), bb, 0, stream>>>(qb, kb, vb, ob);
    out_gemm<<<gg, bb, 0, stream>>>(ob, Wo, bo, out);
}

// Round 2
// 479.608 us; speedup vs baseline: 2.3033x; 2.3033x over previous
//
#include <hip/hip_runtime.h>

// B=2, S=4096, D=768, H=12, HD=64
#define Sq 4096
#define Dm 768
#define Hh 12
#define KD 768

typedef short short8 __attribute__((ext_vector_type(8)));
typedef float f32x4 __attribute__((ext_vector_type(4)));
typedef unsigned short bf_t;

__device__ inline bf_t f2bf(float f) {
    unsigned int u = __builtin_bit_cast(unsigned int, f);
    u += 0x7fffu + ((u >> 16) & 1u);   // RNE
    return (bf_t)(u >> 16);
}

// async 16B global->LDS (wave-uniform LDS base + lane*16)
__device__ inline void gl_lds16(const void* g, void* l) {
    __builtin_amdgcn_global_load_lds(
        (const __attribute__((address_space(1))) unsigned int*)g,
        (__attribute__((address_space(3))) unsigned int*)l, 16, 0, 0);
}

// ---------------- fp32 -> bf16 convert (memory-bound) ----------------
__global__ __launch_bounds__(256) void cvt(const float* __restrict__ s,
                                           bf_t* __restrict__ d, int n) {
    int i = (blockIdx.x * 256 + threadIdx.x) * 8;
    if (i < n) {
        float4 a = *(const float4*)(s + i);
        float4 b = *(const float4*)(s + i + 4);
        short8 p;
        p[0] = (short)f2bf(a.x); p[1] = (short)f2bf(a.y);
        p[2] = (short)f2bf(a.z); p[3] = (short)f2bf(a.w);
        p[4] = (short)f2bf(b.x); p[5] = (short)f2bf(b.y);
        p[6] = (short)f2bf(b.z); p[7] = (short)f2bf(b.w);
        *(short8*)(d + i) = p;
    }
}

// ---------------- bf16 GEMM: C = A (MxK) * B^T (NxK) + bias ----------------
// 128x128 tile, BK=64, global_load_lds staging, XOR-swizzled 16B chunks.
// MODE 0: bf16 out, head-split [B,H,S,HD], bias over n, *scale
// MODE 1: bf16 out, V^T layout [B,H,HD,S]  (A=W rows=features, B=X rows=tokens), bias over m
// MODE 2: fp32 out row-major [M,N], bias over n
template <int MODE>
__global__ __launch_bounds__(256) void gemm_k(const bf_t* __restrict__ A,
                                              const bf_t* __restrict__ Bm,
                                              const float* __restrict__ bias,
                                              void* __restrict__ outp, float scale) {
    __shared__ bf_t As[128 * 64];
    __shared__ bf_t Bs[128 * 64];
    const int lane = threadIdx.x & 63, wv = threadIdx.x >> 6;
    const int l16 = lane & 15, quad = lane >> 4;
    const int wm = wv >> 1, wn = wv & 1;
    const int m0 = blockIdx.x * 128, n0 = blockIdx.y * 128;

    f32x4 acc[4][4] = {};

    for (int kk = 0; kk < KD; kk += 64) {
#pragma unroll
        for (int it = 0; it < 4; ++it) {
            int p0 = it * 256 + wv * 64;
            int p = p0 + lane;
            int row = p >> 3;
            int c = (p & 7) ^ (row & 7);          // logical chunk for this physical slot
            gl_lds16(A + (size_t)(m0 + row) * KD + kk + c * 8, As + p0 * 8);
            gl_lds16(Bm + (size_t)(n0 + row) * KD + kk + c * 8, Bs + p0 * 8);
        }
        __syncthreads();
#pragma unroll
        for (int ks = 0; ks < 2; ++ks) {
            short8 a[4], b[4];
#pragma unroll
            for (int i = 0; i < 4; ++i) {
                int row = wm * 64 + i * 16 + l16;
                int pc = (ks * 4 + quad) ^ (row & 7);
                a[i] = *(const short8*)&As[row * 64 + pc * 8];
            }
#pragma unroll
            for (int j = 0; j < 4; ++j) {
                int row = wn * 64 + j * 16 + l16;
                int pc = (ks * 4 + quad) ^ (row & 7);
                b[j] = *(const short8*)&Bs[row * 64 + pc * 8];
            }
#pragma unroll
            for (int i = 0; i < 4; ++i)
#pragma unroll
                for (int j = 0; j < 4; ++j)
                    acc[i][j] = __builtin_amdgcn_mfma_f32_16x16x32_bf16(a[i], b[j], acc[i][j], 0, 0, 0);
        }
        __syncthreads();
    }

#pragma unroll
    for (int i = 0; i < 4; ++i) {
#pragma unroll
        for (int j = 0; j < 4; ++j) {
            int grow = m0 + wm * 64 + i * 16 + quad * 4;
            int gcol = n0 + wn * 64 + j * 16 + l16;
            if (MODE == 0) {
                float bv = bias[gcol];
                int h = gcol >> 6, hd = gcol & 63;
                bf_t* dst = (bf_t*)outp;
#pragma unroll
                for (int r = 0; r < 4; ++r) {
                    int row = grow + r;
                    int bI = row >> 12, s = row & 4095;
                    dst[(((size_t)(bI * Hh + h) * Sq + s) << 6) + hd] =
                        f2bf((acc[i][j][r] + bv) * scale);
                }
            } else if (MODE == 1) {
                bf_t* dst = (bf_t*)outp;
                int t = gcol, bI = t >> 12, s = t & 4095;
#pragma unroll
                for (int r = 0; r < 4; ++r) {
                    int f = grow + r;
                    int h = f >> 6, hd = f & 63;
                    dst[((size_t)(bI * Hh + h) * 64 + hd) * Sq + s] = f2bf(acc[i][j][r] + bias[f]);
                }
            } else {
                float bv = bias[gcol];
                float* dst = (float*)outp;
#pragma unroll
                for (int r = 0; r < 4; ++r)
                    dst[(size_t)(grow + r) * Dm + gcol] = acc[i][j][r] + bv;
            }
        }
    }
}

// ---------------- flash attention, causal ----------------
// Q,K: [B*H, S, 64] bf16 (Q pre-scaled). VT: [B*H, 64, S] bf16.
// 4 independent waves per block, 32 q-rows per wave, no barriers.
__global__ __launch_bounds__(256) void attn(const bf_t* __restrict__ Q,
                                            const bf_t* __restrict__ K,
                                            const bf_t* __restrict__ VT,
                                            bf_t* __restrict__ O) {
    const int bh = blockIdx.x;
    const int qt = gridDim.y - 1 - blockIdx.y;     // long blocks first
    const int lane = threadIdx.x & 63, wv = threadIdx.x >> 6;
    const int l16 = lane & 15, quad = lane >> 4;
    const int b = bh / Hh, h = bh % Hh;
    const size_t base = (size_t)bh * Sq * 64;
    const int q0 = qt * 128 + wv * 32;

    __shared__ bf_t p_lds[4][32][72];   // per-wave; stride 72 -> 16B-aligned rows

    short8 qf[2][2];
#pragma unroll
    for (int i = 0; i < 2; ++i) {
        const bf_t* qp = Q + base + (size_t)(q0 + i * 16 + l16) * 64 + quad * 8;
        qf[i][0] = *(const short8*)qp;
        qf[i][1] = *(const short8*)(qp + 32);
    }

    f32x4 oacc[2][4] = {};
    float m_i[2][4], l_i[2][4];
#pragma unroll
    for (int i = 0; i < 2; ++i)
#pragma unroll
        for (int r = 0; r < 4; ++r) { m_i[i][r] = -__builtin_inff(); l_i[i][r] = 0.f; }

    const int nkt = ((q0 + 31) >> 6) + 1;          // per-wave causal bound
    for (int kt = 0; kt < nkt; ++kt) {
        const int kv0 = kt * 64;
        f32x4 s[2][4];
#pragma unroll
        for (int nt = 0; nt < 4; ++nt) {
            const bf_t* kp = K + base + (size_t)(kv0 + nt * 16 + l16) * 64 + quad * 8;
            short8 klo = *(const short8*)kp;
            short8 khi = *(const short8*)(kp + 32);
#pragma unroll
            for (int i = 0; i < 2; ++i) {
                f32x4 z = {};
                z = __builtin_amdgcn_mfma_f32_16x16x32_bf16(qf[i][0], klo, z, 0, 0, 0);
                s[i][nt] = __builtin_amdgcn_mfma_f32_16x16x32_bf16(qf[i][1], khi, z, 0, 0, 0);
            }
        }
#pragma unroll
        for (int i = 0; i < 2; ++i) {
            if (kv0 + 63 > q0 + i * 16) {          // wave-uniform: diagonal tiles only
#pragma unroll
                for (int nt = 0; nt < 4; ++nt)
#pragma unroll
                    for (int r = 0; r < 4; ++r) {
                        int col = kv0 + nt * 16 + l16;
                        int row = q0 + i * 16 + quad * 4 + r;
                        if (col > row) s[i][nt][r] = -__builtin_inff();
                    }
            }
            float alpha[4];
#pragma unroll
            for (int r = 0; r < 4; ++r) {
                float mx = fmaxf(fmaxf(s[i][0][r], s[i][1][r]), fmaxf(s[i][2][r], s[i][3][r]));
#pragma unroll
                for (int off = 1; off < 16; off <<= 1)
                    mx = fmaxf(mx, __shfl_xor(mx, off, 64));
                float mnew = fmaxf(m_i[i][r], mx);
                float a = __expf(m_i[i][r] - mnew);
                float ps = 0.f;
#pragma unroll
                for (int nt = 0; nt < 4; ++nt) {
                    float p = __expf(s[i][nt][r] - mnew);
                    s[i][nt][r] = p;
                    ps += p;
                }
#pragma unroll
                for (int off = 1; off < 16; off <<= 1)
                    ps += __shfl_xor(ps, off, 64);
                l_i[i][r] = l_i[i][r] * a + ps;
                m_i[i][r] = mnew;
                alpha[r] = a;
            }
#pragma unroll
            for (int ot = 0; ot < 4; ++ot)
#pragma unroll
                for (int r = 0; r < 4; ++r) oacc[i][ot][r] *= alpha[r];
#pragma unroll
            for (int nt = 0; nt < 4; ++nt)
#pragma unroll
                for (int r = 0; r < 4; ++r)
                    p_lds[wv][i * 16 + quad * 4 + r][nt * 16 + l16] = f2bf(s[i][nt][r]);
        }
        // same-wave LDS write->read: in-order, no barrier needed
        short8 pf[2][2];
#pragma unroll
        for (int i = 0; i < 2; ++i) {
            pf[i][0] = *(const short8*)&p_lds[wv][i * 16 + l16][quad * 8];
            pf[i][1] = *(const short8*)&p_lds[wv][i * 16 + l16][32 + quad * 8];
        }
#pragma unroll
        for (int ot = 0; ot < 4; ++ot) {
            const bf_t* vp = VT + base + (size_t)(ot * 16 + l16) * Sq + kv0 + quad * 8;
            short8 vlo = *(const short8*)vp;
            short8 vhi = *(const short8*)(vp + 32);
#pragma unroll
            for (int i = 0; i < 2; ++i) {
                oacc[i][ot] = __builtin_amdgcn_mfma_f32_16x16x32_bf16(pf[i][0], vlo, oacc[i][ot], 0, 0, 0);
                oacc[i][ot] = __builtin_amdgcn_mfma_f32_16x16x32_bf16(pf[i][1], vhi, oacc[i][ot], 0, 0, 0);
            }
        }
    }

#pragma unroll
    for (int i = 0; i < 2; ++i)
#pragma unroll
        for (int r = 0; r < 4; ++r) {
            float inv = 1.f / l_i[i][r];
            int srow = q0 + i * 16 + quad * 4 + r;
#pragma unroll
            for (int ot = 0; ot < 4; ++ot)
                O[(size_t)(b * Sq + srow) * Dm + h * 64 + ot * 16 + l16] =
                    f2bf(oacc[i][ot][r] * inv);
        }
}

extern "C" void kernel_launch(void* const* d_in, const int* in_sizes, int n_in,
                              void* d_out, int out_size, void* d_ws, size_t ws_size,
                              hipStream_t stream) {
    const float* q  = (const float*)d_in[0];
    const float* k  = (const float*)d_in[1];
    const float* v  = (const float*)d_in[2];
    // d_in[3]: causal mask — analytic
    const float* Wq = (const float*)d_in[4];  const float* bq = (const float*)d_in[5];
    const float* Wk = (const float*)d_in[6];  const float* bk = (const float*)d_in[7];
    const float* Wv = (const float*)d_in[8];  const float* bv = (const float*)d_in[9];
    const float* Wo = (const float*)d_in[10]; const float* bo = (const float*)d_in[11];
    float* out = (float*)d_out;

    const size_t NTOK = (size_t)2 * Sq * Dm;   // 6291456
    const size_t NW   = (size_t)Dm * Dm;       // 589824
    bf_t* qb  = (bf_t*)d_ws;
    bf_t* kb  = qb + NTOK;
    bf_t* vb  = kb + NTOK;
    bf_t* ob  = vb + NTOK;
    bf_t* xc  = ob + NTOK;                      // reusable converted-X buffer
    bf_t* wqb = xc + NTOK;
    bf_t* wkb = wqb + NW;
    bf_t* wvb = wkb + NW;
    bf_t* wob = wvb + NW;

    dim3 b256(256);
    cvt<<<288, b256, 0, stream>>>(Wq, wqb, (int)NW);
    cvt<<<288, b256, 0, stream>>>(Wk, wkb, (int)NW);
    cvt<<<288, b256, 0, stream>>>(Wv, wvb, (int)NW);
    cvt<<<288, b256, 0, stream>>>(Wo, wob, (int)NW);

    dim3 gproj(64, 6);   // M=8192 tiles x N=768 tiles
    dim3 gvt(6, 64);     // M=768 (features) x N=8192 (tokens)

    cvt<<<3072, b256, 0, stream>>>(q, xc, (int)NTOK);
    gemm_k<0><<<gproj, b256, 0, stream>>>(xc, wqb, bq, qb, 0.125f);  // 1/sqrt(64) folded
    cvt<<<3072, b256, 0, stream>>>(k, xc, (int)NTOK);
    gemm_k<0><<<gproj, b256, 0, stream>>>(xc, wkb, bk, kb, 1.0f);
    cvt<<<3072, b256, 0, stream>>>(v, xc, (int)NTOK);
    gemm_k<1><<<gvt, b256, 0, stream>>>(wvb, xc, bv, vb, 1.0f);      // V^T direct

    attn<<<dim3(2 * Hh, Sq / 128), b256, 0, stream>>>(qb, kb, vb, ob);
    gemm_k<2><<<gproj, b256, 0, stream>>>(ob, wob, bo, out, 1.0f);
}